// Round 6
// baseline (64.283 us; speedup 1.0000x reference)
//
#include <hip/hip_runtime.h>
#include <math.h>

#define A_N 2048
#define L_N 512
#define D 128
#define B_N 64
#define H1_N 512
#define H2_N 256
#define PST 136   // bf16 LDS row stride

typedef __attribute__((ext_vector_type(8))) short short8;
typedef __attribute__((ext_vector_type(4))) float f32x4;

__device__ __forceinline__ int lb_dev(const int* __restrict__ arr, int n, int val) {
    int lo = 0, hi = n;
    while (lo < hi) { int mid = (lo + hi) >> 1; if (arr[mid] < val) lo = mid + 1; else hi = mid; }
    return lo;
}

__device__ __forceinline__ unsigned short f2bf(float f) {
    unsigned int u = __float_as_uint(f);
    return (unsigned short)((u + 0x7FFFu + ((u >> 16) & 1u)) >> 16);
}
__device__ __forceinline__ float bf2f(unsigned short h) {
    return __uint_as_float(((unsigned int)h) << 16);
}

// ================= K123: per-molecule scores + pools -> HcT =================
// 64 blocks, block b = molecule b. Fully self-contained.
__global__ __launch_bounds__(256) void k123(const float* __restrict__ atom_embed,
                                            const float* __restrict__ prot,
                                            const int* __restrict__ splits,
                                            const float* __restrict__ W_att,
                                            const float* __restrict__ bo,
                                            float* __restrict__ HcT,
                                            float* __restrict__ out) {
    __shared__ unsigned short Ph[32 * PST], Pl[32 * PST];   // P chunk hi/lo
    __shared__ unsigned short Xh[64 * PST], Xl[64 * PST];   // X tile hi/lo
    __shared__ float cmax_all[512];
    __shared__ float rm[64];
    __shared__ float rm_part[4][64];
    __shared__ float cm_part[2][32];
    __shared__ float ews[32];
    __shared__ float ea_lds[64];
    __shared__ float4 pred[8][32];
    __shared__ float zacc_s, sc_acc_s;

    const int tid = threadIdx.x;
    const int b = blockIdx.x;
    if (b == 0 && tid < B_N) out[tid] = bo[0];
    const int s = lb_dev(splits, A_N, b);
    const int e = lb_dev(splits, A_N, b + 1);
    const int n = e - s;

    cmax_all[tid] = -INFINITY;
    cmax_all[tid + 256] = -INFINITY;
    if (tid < 64) rm[tid] = -INFINITY;
    if (tid == 0) { zacc_s = 0.f; sc_acc_s = 0.f; }

    const int lane = tid & 63;
    const int w = tid >> 6;          // wave 0..3
    const int col = lane & 15;
    const int kb = lane >> 4;        // 0..3
    const int c4 = tid & 31;         // float4 column for staging/pools
    const int rg = tid >> 5;         // 0..7 row group

    float4 pool4 = {0.f, 0.f, 0.f, 0.f};
    float4 pp4   = {0.f, 0.f, 0.f, 0.f};

    for (int a0 = 0; a0 < n; a0 += 64) {
        const int an = min(64, n - a0);
        const bool isLast = (a0 + 64 >= n);

        // ---------- Phase X: X[a0..a0+an) = atom @ W_att via split-bf16 MFMA ----------
        __syncthreads();   // prior atile LDS use complete
        {
            // B-frags from W_att (strided gather; wave w owns d-tiles 2w, 2w+1)
            short8 WBh[2][4], WBl[2][4];
            #pragma unroll
            for (int ff = 0; ff < 2; ++ff) {
                const int dcol = (w * 2 + ff) * 16 + col;
                #pragma unroll
                for (int ks = 0; ks < 4; ++ks) {
                    short8 bh, bl;
                    #pragma unroll
                    for (int j = 0; j < 8; ++j) {
                        const float wv = W_att[(size_t)(ks * 32 + kb * 8 + j) * D + dcol];
                        const unsigned short h = f2bf(wv);
                        bh[j] = (short)h;
                        bl[j] = (short)f2bf(wv - bf2f(h));
                    }
                    WBh[ff][ks] = bh; WBl[ff][ks] = bl;
                }
            }
            #pragma unroll
            for (int mt = 0; mt < 4; ++mt) {
                const int ar = mt * 16 + col;
                const bool va = ar < an;
                short8 Ah[4], Al[4];
                #pragma unroll
                for (int ks = 0; ks < 4; ++ks) {
                    float4 v0 = {0.f,0.f,0.f,0.f}, v1 = {0.f,0.f,0.f,0.f};
                    if (va) {
                        const float4* p = (const float4*)(atom_embed + (size_t)(s + a0 + ar) * D)
                                          + ks * 8 + kb * 2;
                        v0 = p[0]; v1 = p[1];
                    }
                    const float vv[8] = {v0.x,v0.y,v0.z,v0.w,v1.x,v1.y,v1.z,v1.w};
                    short8 ah, al;
                    #pragma unroll
                    for (int j = 0; j < 8; ++j) {
                        const unsigned short h = f2bf(vv[j]);
                        ah[j] = (short)h;
                        al[j] = (short)f2bf(vv[j] - bf2f(h));
                    }
                    Ah[ks] = ah; Al[ks] = al;
                }
                #pragma unroll
                for (int ff = 0; ff < 2; ++ff) {
                    f32x4 acc = {0.f, 0.f, 0.f, 0.f};
                    #pragma unroll
                    for (int ks = 0; ks < 4; ++ks) {
                        acc = __builtin_amdgcn_mfma_f32_16x16x32_bf16(Ah[ks], WBh[ff][ks], acc, 0, 0, 0);
                        acc = __builtin_amdgcn_mfma_f32_16x16x32_bf16(Ah[ks], WBl[ff][ks], acc, 0, 0, 0);
                        acc = __builtin_amdgcn_mfma_f32_16x16x32_bf16(Al[ks], WBh[ff][ks], acc, 0, 0, 0);
                    }
                    const int dcol = (w * 2 + ff) * 16 + col;
                    #pragma unroll
                    for (int i = 0; i < 4; ++i) {
                        const int arow = mt * 16 + kb * 4 + i;
                        const unsigned short h = f2bf(acc[i]);
                        Xh[arow * PST + dcol] = h;
                        Xl[arow * PST + dcol] = f2bf(acc[i] - bf2f(h));
                    }
                }
            }
        }
        __syncthreads();

        // A-frags of X held in registers across all chunks (wave w: mts {w>>1, (w>>1)+2})
        short8 XAh[2][4], XAl[2][4];
        #pragma unroll
        for (int m = 0; m < 2; ++m) {
            const int mrow = ((w >> 1) + m * 2) * 16 + col;
            #pragma unroll
            for (int ks = 0; ks < 4; ++ks) {
                XAh[m][ks] = *(const short8*)(Xh + mrow * PST + ks * 32 + kb * 8);
                XAl[m][ks] = *(const short8*)(Xl + mrow * PST + ks * 32 + kb * 8);
            }
        }

        // ---------- chunk loop: 16 chunks of 32 residues ----------
        for (int ch = 0; ch < 16; ++ch) {
            __syncthreads();   // prior chunk's Ph/Pl reads + pv use complete
            float4 pv[4];
            {
                const float4* src = (const float4*)(prot + ((size_t)b * L_N + ch * 32) * D);
                #pragma unroll
                for (int kq = 0; kq < 4; ++kq) {
                    const int i = tid + kq * 256;
                    pv[kq] = src[i];
                    const int row = i >> 5, q = (i & 31) * 4;
                    ushort4 h, lo;
                    h.x = f2bf(pv[kq].x); lo.x = f2bf(pv[kq].x - bf2f(h.x));
                    h.y = f2bf(pv[kq].y); lo.y = f2bf(pv[kq].y - bf2f(h.y));
                    h.z = f2bf(pv[kq].z); lo.z = f2bf(pv[kq].z - bf2f(h.z));
                    h.w = f2bf(pv[kq].w); lo.w = f2bf(pv[kq].w - bf2f(h.w));
                    *(ushort4*)(Ph + row * PST + q) = h;
                    *(ushort4*)(Pl + row * PST + q) = lo;
                }
            }
            ((float*)rm_part)[tid] = -INFINITY;
            __syncthreads();

            const int nt = w & 1;
            short8 PBh[4], PBl[4];
            #pragma unroll
            for (int ks = 0; ks < 4; ++ks) {
                PBh[ks] = *(const short8*)(Ph + (nt * 16 + col) * PST + ks * 32 + kb * 8);
                PBl[ks] = *(const short8*)(Pl + (nt * 16 + col) * PST + ks * 32 + kb * 8);
            }
            float cm_w = -INFINITY;
            #pragma unroll
            for (int m = 0; m < 2; ++m) {
                f32x4 acc = {0.f, 0.f, 0.f, 0.f};
                #pragma unroll
                for (int ks = 0; ks < 4; ++ks) {
                    acc = __builtin_amdgcn_mfma_f32_16x16x32_bf16(XAh[m][ks], PBh[ks], acc, 0, 0, 0);
                    acc = __builtin_amdgcn_mfma_f32_16x16x32_bf16(XAh[m][ks], PBl[ks], acc, 0, 0, 0);
                    acc = __builtin_amdgcn_mfma_f32_16x16x32_bf16(XAl[m][ks], PBh[ks], acc, 0, 0, 0);
                }
                const int mt = (w >> 1) + m * 2;
                // rowmax over this wave's 16 l's
                float r0 = acc[0], r1 = acc[1], r2 = acc[2], r3 = acc[3];
                #pragma unroll
                for (int off = 1; off <= 8; off <<= 1) {
                    r0 = fmaxf(r0, __shfl_xor(r0, off));
                    r1 = fmaxf(r1, __shfl_xor(r1, off));
                    r2 = fmaxf(r2, __shfl_xor(r2, off));
                    r3 = fmaxf(r3, __shfl_xor(r3, off));
                }
                if (col == 0) {
                    rm_part[w][mt * 16 + kb * 4 + 0] = r0;
                    rm_part[w][mt * 16 + kb * 4 + 1] = r1;
                    rm_part[w][mt * 16 + kb * 4 + 2] = r2;
                    rm_part[w][mt * 16 + kb * 4 + 3] = r3;
                }
                // colmax over valid atoms
                const int rb = mt * 16 + kb * 4;
                float cm = -INFINITY;
                if (rb + 0 < an) cm = fmaxf(cm, acc[0]);
                if (rb + 1 < an) cm = fmaxf(cm, acc[1]);
                if (rb + 2 < an) cm = fmaxf(cm, acc[2]);
                if (rb + 3 < an) cm = fmaxf(cm, acc[3]);
                cm = fmaxf(cm, __shfl_xor(cm, 16));
                cm = fmaxf(cm, __shfl_xor(cm, 32));
                cm_w = fmaxf(cm_w, cm);
            }
            if (kb == 0) cm_part[w >> 1][nt * 16 + col] = cm_w;
            __syncthreads();

            if (tid < 64) {
                const float m4 = fmaxf(fmaxf(rm_part[0][tid], rm_part[1][tid]),
                                       fmaxf(rm_part[2][tid], rm_part[3][tid]));
                rm[tid] = fmaxf(rm[tid], m4);
            }
            if (tid < 32) {
                const float cm = fmaxf(cm_part[0][tid], cm_part[1][tid]);
                const float cl = fmaxf(cmax_all[ch * 32 + tid], cm);
                cmax_all[ch * 32 + tid] = cl;
                if (isLast) {
                    float ev = expf(cl);
                    ews[tid] = ev;
                    #pragma unroll
                    for (int off = 1; off <= 16; off <<= 1) ev += __shfl_xor(ev, off);
                    if (tid == 0) zacc_s += ev;
                }
            }
            __syncthreads();

            if (isLast) {
                #pragma unroll
                for (int kq = 0; kq < 4; ++kq) {
                    const float wgt = ews[rg + kq * 8];
                    pp4.x += wgt * pv[kq].x;
                    pp4.y += wgt * pv[kq].y;
                    pp4.z += wgt * pv[kq].z;
                    pp4.w += wgt * pv[kq].w;
                }
            }
        }

        // ---------- atile epilogue: atom exp + pool partial ----------
        if (tid < 64) {
            float ea = (tid < an) ? expf(rm[tid]) : 0.f;
            ea_lds[tid] = ea;
            rm[tid] = -INFINITY;
            #pragma unroll
            for (int off = 1; off <= 32; off <<= 1) ea += __shfl_xor(ea, off);
            if (tid == 0) sc_acc_s += ea;
        }
        __syncthreads();
        {
            const float4* ae4 = (const float4*)atom_embed;
            for (int a = rg; a < an; a += 8) {
                const float c = ea_lds[a];
                const float4 v = ae4[(size_t)(s + a0 + a) * (D / 4) + c4];
                pool4.x += c * v.x; pool4.y += c * v.y;
                pool4.z += c * v.z; pool4.w += c * v.w;
            }
        }
    }

    // ---------- final: write HcT ----------
    __syncthreads();
    pred[rg][c4] = pool4;
    __syncthreads();
    if (tid < 32) {
        float4 acc = pred[0][tid];
        #pragma unroll
        for (int gg = 1; gg < 8; ++gg) {
            const float4 t = pred[gg][tid];
            acc.x += t.x; acc.y += t.y; acc.z += t.z; acc.w += t.w;
        }
        const float invSc = 1.f / sc_acc_s;
        HcT[(size_t)(tid * 4 + 0) * B_N + b] = acc.x * invSc;
        HcT[(size_t)(tid * 4 + 1) * B_N + b] = acc.y * invSc;
        HcT[(size_t)(tid * 4 + 2) * B_N + b] = acc.z * invSc;
        HcT[(size_t)(tid * 4 + 3) * B_N + b] = acc.w * invSc;
    }
    __syncthreads();
    pred[rg][c4] = pp4;
    __syncthreads();
    if (tid < 32) {
        float4 acc = pred[0][tid];
        #pragma unroll
        for (int gg = 1; gg < 8; ++gg) {
            const float4 t = pred[gg][tid];
            acc.x += t.x; acc.y += t.y; acc.z += t.z; acc.w += t.w;
        }
        const float invZ = 1.f / zacc_s;
        HcT[(size_t)(D + tid * 4 + 0) * B_N + b] = acc.x * invZ;
        HcT[(size_t)(D + tid * 4 + 1) * B_N + b] = acc.y * invZ;
        HcT[(size_t)(D + tid * 4 + 2) * B_N + b] = acc.z * invZ;
        HcT[(size_t)(D + tid * 4 + 3) * B_N + b] = acc.w * invZ;
    }
}

// ---------- K4: H1T = relu(Hc @ W1 + b1)^T ----------
__global__ __launch_bounds__(256) void k4_h1(const float* __restrict__ HcT,
                                             const float* __restrict__ W1,
                                             const float* __restrict__ b1,
                                             float* __restrict__ H1T) {
    __shared__ float hr[4][64];
    const int tid = threadIdx.x;
    const int m = tid & 63;
    const int jh = (tid >> 6) & 1;
    const int kh = tid >> 7;
    const int j = blockIdx.x * 2 + jh;
    float acc = 0.f;
    const int k0 = kh * 128;
    #pragma unroll 8
    for (int k = k0; k < k0 + 128; ++k)
        acc += HcT[(size_t)k * B_N + m] * W1[(size_t)k * H1_N + j];
    hr[jh * 2 + kh][m] = acc;
    __syncthreads();
    if (kh == 0)
        H1T[(size_t)j * B_N + m] = fmaxf(hr[jh * 2][m] + hr[jh * 2 + 1][m] + b1[j], 0.f);
}

// ---------- K5: H2 + output atomics ----------
__global__ __launch_bounds__(256) void k5_h2(const float* __restrict__ H1T,
                                             const float* __restrict__ W2,
                                             const float* __restrict__ b2,
                                             const float* __restrict__ Wo,
                                             float* __restrict__ out) {
    __shared__ float hr[4][64];
    const int tid = threadIdx.x;
    const int m = tid & 63;
    const int kq = tid >> 6;
    const int j = blockIdx.x;
    float acc = 0.f;
    const int k0 = kq * 128;
    #pragma unroll 8
    for (int k = k0; k < k0 + 128; ++k)
        acc += H1T[(size_t)k * B_N + m] * W2[(size_t)k * H2_N + j];
    hr[kq][m] = acc;
    __syncthreads();
    if (kq == 0) {
        const float h2 = fmaxf(hr[0][m] + hr[1][m] + hr[2][m] + hr[3][m] + b2[j], 0.f);
        atomicAdd(out + m, h2 * Wo[j]);
    }
}

extern "C" void kernel_launch(void* const* d_in, const int* in_sizes, int n_in,
                              void* d_out, int out_size, void* d_ws, size_t ws_size,
                              hipStream_t stream) {
    const float* atom_embed = (const float*)d_in[0];
    const float* prot       = (const float*)d_in[1];
    const int*   splits     = (const int*)d_in[2];
    const float* W_att      = (const float*)d_in[3];
    const float* W1         = (const float*)d_in[4];
    const float* b1         = (const float*)d_in[5];
    const float* W2         = (const float*)d_in[6];
    const float* b2         = (const float*)d_in[7];
    const float* Wo         = (const float*)d_in[8];
    const float* bo         = (const float*)d_in[9];
    float* out = (float*)d_out;

    float* ws = (float*)d_ws;
    float* HcT = ws;  ws += 2 * D * B_N;   // 16384
    float* H1T = ws;  ws += H1_N * B_N;    // 32768

    hipLaunchKernelGGL(k123, dim3(B_N),      dim3(256), 0, stream,
                       atom_embed, prot, splits, W_att, bo, HcT, out);
    hipLaunchKernelGGL(k4_h1, dim3(H1_N / 2), dim3(256), 0, stream, HcT, W1, b1, H1T);
    hipLaunchKernelGGL(k5_h2, dim3(H2_N),     dim3(256), 0, stream, H1T, W2, b2, Wo, out);
}

// Round 7
// 49.660 us; speedup vs baseline: 1.2945x; 1.2945x over previous
//
#include <hip/hip_runtime.h>
#include <math.h>

#define A_N 2048
#define L_N 512
#define D 128
#define B_N 64
#define H1_N 512
#define H2_N 256
#define NCHUNK 16
#define CL 32     // residues per k2 block

typedef __attribute__((ext_vector_type(8))) short short8;
typedef __attribute__((ext_vector_type(4))) float f32x4;

__device__ __forceinline__ int lb_dev(const int* __restrict__ arr, int n, int val) {
    int lo = 0, hi = n;
    while (lo < hi) { int mid = (lo + hi) >> 1; if (arr[mid] < val) lo = mid + 1; else hi = mid; }
    return lo;
}

__device__ __forceinline__ float blk_sum(float v, float* red, int tid) {
    #pragma unroll
    for (int off = 32; off >= 1; off >>= 1) v += __shfl_xor(v, off);
    __syncthreads();
    if ((tid & 63) == 0) red[tid >> 6] = v;
    __syncthreads();
    return red[0] + red[1] + red[2] + red[3];
}

__device__ __forceinline__ unsigned short f2bf(float f) {
    unsigned int u = __float_as_uint(f);
    return (unsigned short)((u + 0x7FFFu + ((u >> 16) & 1u)) >> 16);
}
__device__ __forceinline__ float bf2f(unsigned short h) {
    return __uint_as_float(((unsigned int)h) << 16);
}

// ---------- K1: X = atom_embed @ W_att -> Xh/Xl (bf16 hi/lo) ; out = bo ----------
__global__ __launch_bounds__(256) void k1_xmul(const float* __restrict__ atom_embed,
                                               const float* __restrict__ W_att,
                                               const float* __restrict__ bo,
                                               unsigned short* __restrict__ Xh,
                                               unsigned short* __restrict__ Xl,
                                               float* __restrict__ out) {
    __shared__ float ae[8][128];
    const int tid = threadIdx.x;
    const int bid = blockIdx.x;
    if (bid == 0 && tid < B_N) out[tid] = bo[0];
    const int a0 = bid * 8;
    float4 v = reinterpret_cast<const float4*>(atom_embed + (size_t)a0 * D)[tid];
    const int fi = tid * 4;
    *reinterpret_cast<float4*>(&ae[fi >> 7][fi & 127]) = v;
    __syncthreads();
    const int d = tid & 127;
    const int ai = tid >> 7;
    float acc0 = 0.f, acc1 = 0.f, acc2 = 0.f, acc3 = 0.f;
    for (int k = 0; k < D; ++k) {
        const float w = W_att[k * D + d];
        acc0 += ae[ai + 0][k] * w;
        acc1 += ae[ai + 2][k] * w;
        acc2 += ae[ai + 4][k] * w;
        acc3 += ae[ai + 6][k] * w;
    }
    float accs[4] = {acc0, acc1, acc2, acc3};
    #pragma unroll
    for (int t = 0; t < 4; ++t) {
        const size_t idx = (size_t)(a0 + ai + 2 * t) * D + d;
        const unsigned short h = f2bf(accs[t]);
        Xh[idx] = h;
        Xl[idx] = f2bf(accs[t] - bf2f(h));
    }
}

// ---------- K2: MFMA scores, no operand LDS. grid = 64 mol x 16 chunks ----------
__global__ __launch_bounds__(256, 3) void k2_scores(const unsigned short* __restrict__ Xh,
                                                    const unsigned short* __restrict__ Xl,
                                                    const float* __restrict__ prot,
                                                    const int* __restrict__ splits,
                                                    float* __restrict__ rowmaxp,
                                                    float* __restrict__ ppart,
                                                    float* __restrict__ eWpart) {
    __shared__ float rm_part[2][128];
    __shared__ float cm_part[2][32];
    __shared__ float ews_s[CL];
    __shared__ float4 pred[8][32];

    const int tid = threadIdx.x;
    const int bid = blockIdx.x;
    const int b = bid & (B_N - 1);
    const int chunk = bid >> 6;           // 0..15
    const int l0 = chunk * CL;
    const int s = lb_dev(splits, A_N, b);
    const int e = lb_dev(splits, A_N, b + 1);
    const int n = e - s;

    const int lane = tid & 63;
    const int w = tid >> 6;               // wave 0..3
    const int col = lane & 15;
    const int kb = lane >> 4;             // 0..3
    const int lt = w & 1;                 // l-tile 0/1
    const int pair = w >> 1;              // atom-tile parity

    ((float*)rm_part)[tid] = -INFINITY;
    if (tid < 64) ((float*)cm_part)[tid] = -INFINITY;
    __syncthreads();

    // B-frags: direct global load from prot, split hi/lo in-reg
    short8 Bh[4], Bl[4];
    {
        const float4* pb = (const float4*)(prot + ((size_t)(b * L_N + l0 + lt * 16 + col)) * D);
        #pragma unroll
        for (int ks = 0; ks < 4; ++ks) {
            const float4 v0 = pb[ks * 8 + kb * 2];
            const float4 v1 = pb[ks * 8 + kb * 2 + 1];
            const float vv[8] = {v0.x, v0.y, v0.z, v0.w, v1.x, v1.y, v1.z, v1.w};
            short8 bh, bl;
            #pragma unroll
            for (int j = 0; j < 8; ++j) {
                const unsigned short h = f2bf(vv[j]);
                bh[j] = (short)h;
                bl[j] = (short)f2bf(vv[j] - bf2f(h));
            }
            Bh[ks] = bh; Bl[ks] = bl;
        }
    }

    float cmrun = -INFINITY;
    for (int at = pair; at * 16 < n; at += 2) {
        const int arow = min(s + at * 16 + col, A_N - 1);
        const unsigned short* xh = Xh + (size_t)arow * D;
        const unsigned short* xl = Xl + (size_t)arow * D;
        short8 Ah[4], Al[4];
        #pragma unroll
        for (int ks = 0; ks < 4; ++ks) {
            Ah[ks] = *(const short8*)(xh + ks * 32 + kb * 8);
            Al[ks] = *(const short8*)(xl + ks * 32 + kb * 8);
        }
        f32x4 aHH = {0.f, 0.f, 0.f, 0.f};
        f32x4 aHL = {0.f, 0.f, 0.f, 0.f};
        f32x4 aLH = {0.f, 0.f, 0.f, 0.f};
        #pragma unroll
        for (int ks = 0; ks < 4; ++ks) {
            aHH = __builtin_amdgcn_mfma_f32_16x16x32_bf16(Ah[ks], Bh[ks], aHH, 0, 0, 0);
            aHL = __builtin_amdgcn_mfma_f32_16x16x32_bf16(Ah[ks], Bl[ks], aHL, 0, 0, 0);
            aLH = __builtin_amdgcn_mfma_f32_16x16x32_bf16(Al[ks], Bh[ks], aLH, 0, 0, 0);
        }
        float r[4];
        #pragma unroll
        for (int i = 0; i < 4; ++i) r[i] = aHH[i] + aHL[i] + aLH[i];

        // rowmax over this tile's 16 l's (lanes differing in bits0..3 share a row)
        float r0 = r[0], r1 = r[1], r2 = r[2], r3 = r[3];
        #pragma unroll
        for (int off = 1; off <= 8; off <<= 1) {
            r0 = fmaxf(r0, __shfl_xor(r0, off));
            r1 = fmaxf(r1, __shfl_xor(r1, off));
            r2 = fmaxf(r2, __shfl_xor(r2, off));
            r3 = fmaxf(r3, __shfl_xor(r3, off));
        }
        if (col == 0) {
            rm_part[lt][at * 16 + kb * 4 + 0] = r0;
            rm_part[lt][at * 16 + kb * 4 + 1] = r1;
            rm_part[lt][at * 16 + kb * 4 + 2] = r2;
            rm_part[lt][at * 16 + kb * 4 + 3] = r3;
        }
        // colmax over valid atoms of this tile
        const int rb = at * 16 + kb * 4;
        float cm = -INFINITY;
        if (rb + 0 < n) cm = fmaxf(cm, r[0]);
        if (rb + 1 < n) cm = fmaxf(cm, r[1]);
        if (rb + 2 < n) cm = fmaxf(cm, r[2]);
        if (rb + 3 < n) cm = fmaxf(cm, r[3]);
        cm = fmaxf(cm, __shfl_xor(cm, 16));
        cm = fmaxf(cm, __shfl_xor(cm, 32));
        cmrun = fmaxf(cmrun, cm);
    }
    if (kb == 0) cm_part[pair][lt * 16 + col] = cmrun;
    __syncthreads();

    if (tid < 128 && tid < n)
        rowmaxp[(size_t)(s + tid) * NCHUNK + chunk] = fmaxf(rm_part[0][tid], rm_part[1][tid]);
    if (tid >= 128 && tid < 128 + CL) {
        const int l = tid - 128;
        ews_s[l] = expf(fmaxf(cm_part[0][l], cm_part[1][l]));
    }
    __syncthreads();

    if (tid < 32) {
        float v = ews_s[tid];
        #pragma unroll
        for (int off = 1; off <= 16; off <<= 1) v += __shfl_xor(v, off);
        if (tid == 0) eWpart[b * NCHUNK + chunk] = v;
    }

    // prot-pool partial: coalesced re-stream of the chunk (L2-hot)
    const int rg = tid >> 5, c4 = tid & 31;
    float4 pp4 = {0.f, 0.f, 0.f, 0.f};
    const float4* src = (const float4*)(prot + ((size_t)b * L_N + l0) * D);
    #pragma unroll
    for (int q = 0; q < 4; ++q) {
        const int i = tid + q * 256;
        const float4 v = src[i];
        const float wgt = ews_s[i >> 5];
        pp4.x += wgt * v.x; pp4.y += wgt * v.y;
        pp4.z += wgt * v.z; pp4.w += wgt * v.w;
    }
    pred[rg][c4] = pp4;
    __syncthreads();
    if (tid < 32) {
        float4 acc = pred[0][tid];
        #pragma unroll
        for (int gg = 1; gg < 8; ++gg) {
            const float4 t = pred[gg][tid];
            acc.x += t.x; acc.y += t.y; acc.z += t.z; acc.w += t.w;
        }
        float* dst = ppart + (size_t)(b * NCHUNK + chunk) * D + tid * 4;
        dst[0] = acc.x; dst[1] = acc.y; dst[2] = acc.z; dst[3] = acc.w;
    }
}

// ---------- K3: per-molecule pools -> HcT [256][64] ----------
__global__ __launch_bounds__(256) void k3_pool(const float* __restrict__ atom_embed,
                                               const int* __restrict__ splits,
                                               const float* __restrict__ rowmaxp,
                                               const float* __restrict__ ppart,
                                               const float* __restrict__ eWpart,
                                               float* __restrict__ HcT) {
    __shared__ float red[4];
    __shared__ float coef[512];
    __shared__ float4 pred[8][32];
    const int tid = threadIdx.x;
    const int b = blockIdx.x;
    const int s = lb_dev(splits, A_N, b);
    const int e = lb_dev(splits, A_N, b + 1);
    const int n = e - s;

    float local = 0.f;
    for (int j = tid; j < n; j += 256) {
        const float* rp = rowmaxp + (size_t)(s + j) * NCHUNK;
        float m = rp[0];
        #pragma unroll
        for (int c = 1; c < NCHUNK; ++c) m = fmaxf(m, rp[c]);
        local += expf(m);
    }
    const float Sc = blk_sum(local, red, tid);

    const int d4 = tid & 31;
    const int ag = tid >> 5;
    const float4* ae4 = reinterpret_cast<const float4*>(atom_embed);
    float4 pool = {0.f, 0.f, 0.f, 0.f};
    for (int t0 = 0; t0 < n; t0 += 512) {
        const int cnt = min(512, n - t0);
        __syncthreads();
        for (int j = tid; j < cnt; j += 256) {
            const float* rp = rowmaxp + (size_t)(s + t0 + j) * NCHUNK;
            float m = rp[0];
            #pragma unroll
            for (int c = 1; c < NCHUNK; ++c) m = fmaxf(m, rp[c]);
            coef[j] = expf(m) / Sc;
        }
        __syncthreads();
        for (int j = ag; j < cnt; j += 8) {
            const float c = coef[j];
            const float4 v = ae4[(size_t)(s + t0 + j) * (D / 4) + d4];
            pool.x += c * v.x; pool.y += c * v.y; pool.z += c * v.z; pool.w += c * v.w;
        }
    }
    __syncthreads();
    pred[ag][d4] = pool;
    __syncthreads();
    if (ag == 0) {
        float4 acc = pred[0][d4];
        #pragma unroll
        for (int gg = 1; gg < 8; ++gg) {
            const float4 t = pred[gg][d4];
            acc.x += t.x; acc.y += t.y; acc.z += t.z; acc.w += t.w;
        }
        HcT[(size_t)(d4 * 4 + 0) * B_N + b] = acc.x;
        HcT[(size_t)(d4 * 4 + 1) * B_N + b] = acc.y;
        HcT[(size_t)(d4 * 4 + 2) * B_N + b] = acc.z;
        HcT[(size_t)(d4 * 4 + 3) * B_N + b] = acc.w;
    }
    if (tid < 128) {
        float v = 0.f, ez = 0.f;
        #pragma unroll
        for (int c = 0; c < NCHUNK; ++c) {
            v  += ppart[(size_t)(b * NCHUNK + c) * D + tid];
            ez += eWpart[b * NCHUNK + c];
        }
        HcT[(size_t)(D + tid) * B_N + b] = v / ez;
    }
}

// ---------- K4: H1T = relu(Hc @ W1 + b1)^T ----------
__global__ __launch_bounds__(256) void k4_h1(const float* __restrict__ HcT,
                                             const float* __restrict__ W1,
                                             const float* __restrict__ b1,
                                             float* __restrict__ H1T) {
    __shared__ float hr[4][64];
    const int tid = threadIdx.x;
    const int m = tid & 63;
    const int jh = (tid >> 6) & 1;
    const int kh = tid >> 7;
    const int j = blockIdx.x * 2 + jh;
    float acc = 0.f;
    const int k0 = kh * 128;
    #pragma unroll 8
    for (int k = k0; k < k0 + 128; ++k)
        acc += HcT[(size_t)k * B_N + m] * W1[(size_t)k * H1_N + j];
    hr[jh * 2 + kh][m] = acc;
    __syncthreads();
    if (kh == 0)
        H1T[(size_t)j * B_N + m] = fmaxf(hr[jh * 2][m] + hr[jh * 2 + 1][m] + b1[j], 0.f);
}

// ---------- K5: H2 + output atomics ----------
__global__ __launch_bounds__(256) void k5_h2(const float* __restrict__ H1T,
                                             const float* __restrict__ W2,
                                             const float* __restrict__ b2,
                                             const float* __restrict__ Wo,
                                             float* __restrict__ out) {
    __shared__ float hr[4][64];
    const int tid = threadIdx.x;
    const int m = tid & 63;
    const int kq = tid >> 6;
    const int j = blockIdx.x;
    float acc = 0.f;
    const int k0 = kq * 128;
    #pragma unroll 8
    for (int k = k0; k < k0 + 128; ++k)
        acc += H1T[(size_t)k * B_N + m] * W2[(size_t)k * H2_N + j];
    hr[kq][m] = acc;
    __syncthreads();
    if (kq == 0) {
        const float h2 = fmaxf(hr[0][m] + hr[1][m] + hr[2][m] + hr[3][m] + b2[j], 0.f);
        atomicAdd(out + m, h2 * Wo[j]);
    }
}

extern "C" void kernel_launch(void* const* d_in, const int* in_sizes, int n_in,
                              void* d_out, int out_size, void* d_ws, size_t ws_size,
                              hipStream_t stream) {
    const float* atom_embed = (const float*)d_in[0];
    const float* prot       = (const float*)d_in[1];
    const int*   splits     = (const int*)d_in[2];
    const float* W_att      = (const float*)d_in[3];
    const float* W1         = (const float*)d_in[4];
    const float* b1         = (const float*)d_in[5];
    const float* W2         = (const float*)d_in[6];
    const float* b2         = (const float*)d_in[7];
    const float* Wo         = (const float*)d_in[8];
    const float* bo         = (const float*)d_in[9];
    float* out = (float*)d_out;

    unsigned short* Xh = (unsigned short*)d_ws;                // A_N*D ushort
    unsigned short* Xl = Xh + (size_t)A_N * D;                 // A_N*D ushort
    float* fp      = (float*)(Xl + (size_t)A_N * D);
    float* rowmaxp = fp;  fp += (size_t)A_N * NCHUNK;          // 32768
    float* ppart   = fp;  fp += (size_t)B_N * NCHUNK * D;      // 131072
    float* eWpart  = fp;  fp += B_N * NCHUNK;                  // 1024
    float* HcT     = fp;  fp += 2 * D * B_N;                   // 16384
    float* H1T     = fp;  fp += H1_N * B_N;                    // 32768

    hipLaunchKernelGGL(k1_xmul,  dim3(A_N / 8),        dim3(256), 0, stream,
                       atom_embed, W_att, bo, Xh, Xl, out);
    hipLaunchKernelGGL(k2_scores, dim3(B_N * NCHUNK),  dim3(256), 0, stream,
                       Xh, Xl, prot, splits, rowmaxp, ppart, eWpart);
    hipLaunchKernelGGL(k3_pool,  dim3(B_N),            dim3(256), 0, stream,
                       atom_embed, splits, rowmaxp, ppart, eWpart, HcT);
    hipLaunchKernelGGL(k4_h1,    dim3(H1_N / 2),       dim3(256), 0, stream, HcT, W1, b1, H1T);
    hipLaunchKernelGGL(k5_h2,    dim3(H2_N),           dim3(256), 0, stream, H1T, W2, b2, Wo, out);
}

// Round 8
// 48.400 us; speedup vs baseline: 1.3282x; 1.0260x over previous
//
#include <hip/hip_runtime.h>
#include <math.h>

#define A_N 2048
#define L_N 512
#define D 128
#define B_N 64
#define H1_N 512
#define H2_N 256
#define NCHUNK 16
#define CL 32     // residues per k2 block

typedef __attribute__((ext_vector_type(8))) short short8;
typedef __attribute__((ext_vector_type(4))) float f32x4;

__device__ __forceinline__ int lb_dev(const int* __restrict__ arr, int n, int val) {
    int lo = 0, hi = n;
    while (lo < hi) { int mid = (lo + hi) >> 1; if (arr[mid] < val) lo = mid + 1; else hi = mid; }
    return lo;
}

__device__ __forceinline__ float blk_sum(float v, float* red, int tid) {
    #pragma unroll
    for (int off = 32; off >= 1; off >>= 1) v += __shfl_xor(v, off);
    __syncthreads();
    if ((tid & 63) == 0) red[tid >> 6] = v;
    __syncthreads();
    return red[0] + red[1] + red[2] + red[3];
}

__device__ __forceinline__ unsigned short f2bf(float f) {
    unsigned int u = __float_as_uint(f);
    return (unsigned short)((u + 0x7FFFu + ((u >> 16) & 1u)) >> 16);
}
__device__ __forceinline__ float bf2f(unsigned short h) {
    return __uint_as_float(((unsigned int)h) << 16);
}

// ---------- K1: X = atom_embed @ W_att -> Xh/Xl ; out = bo ; segoff ----------
__global__ __launch_bounds__(256) void k1_xmul(const float* __restrict__ atom_embed,
                                               const float* __restrict__ W_att,
                                               const float* __restrict__ bo,
                                               const int* __restrict__ splits,
                                               unsigned short* __restrict__ Xh,
                                               unsigned short* __restrict__ Xl,
                                               float* __restrict__ out,
                                               int* __restrict__ segoff) {
    __shared__ float ae[8][128];
    const int tid = threadIdx.x;
    const int bid = blockIdx.x;
    if (bid == 0) {
        if (tid < B_N) out[tid] = bo[0];
        if (tid <= B_N) segoff[tid] = lb_dev(splits, A_N, tid);
    }
    const int a0 = bid * 8;
    float4 v = reinterpret_cast<const float4*>(atom_embed + (size_t)a0 * D)[tid];
    const int fi = tid * 4;
    *reinterpret_cast<float4*>(&ae[fi >> 7][fi & 127]) = v;
    __syncthreads();
    const int d = tid & 127;
    const int ai = tid >> 7;
    float acc0 = 0.f, acc1 = 0.f, acc2 = 0.f, acc3 = 0.f;
    #pragma unroll 16
    for (int k = 0; k < D; ++k) {
        const float w = W_att[k * D + d];
        acc0 += ae[ai + 0][k] * w;
        acc1 += ae[ai + 2][k] * w;
        acc2 += ae[ai + 4][k] * w;
        acc3 += ae[ai + 6][k] * w;
    }
    float accs[4] = {acc0, acc1, acc2, acc3};
    #pragma unroll
    for (int t = 0; t < 4; ++t) {
        const size_t idx = (size_t)(a0 + ai + 2 * t) * D + d;
        const unsigned short h = f2bf(accs[t]);
        Xh[idx] = h;
        Xl[idx] = f2bf(accs[t] - bf2f(h));
    }
}

// ---------- K2: MFMA scores, no operand LDS. grid = 64 mol x 16 chunks ----------
__global__ __launch_bounds__(256, 3) void k2_scores(const unsigned short* __restrict__ Xh,
                                                    const unsigned short* __restrict__ Xl,
                                                    const float* __restrict__ prot,
                                                    const int* __restrict__ segoff,
                                                    float* __restrict__ rowmaxp,
                                                    float* __restrict__ ppart,
                                                    float* __restrict__ eWpart) {
    __shared__ float rm_part[2][128];
    __shared__ float cm_part[2][32];
    __shared__ float ews_s[CL];
    __shared__ float4 pred[8][32];

    const int tid = threadIdx.x;
    const int bid = blockIdx.x;
    const int b = bid & (B_N - 1);
    const int chunk = bid >> 6;           // 0..15
    const int l0 = chunk * CL;

    const int lane = tid & 63;
    const int w = tid >> 6;               // wave 0..3
    const int col = lane & 15;
    const int kb = lane >> 4;             // 0..3
    const int lt = w & 1;                 // l-tile 0/1
    const int pair = w >> 1;              // atom-tile parity

    // B-frags first: direct global load from prot, split hi/lo in-reg (issue early)
    short8 Bh[4], Bl[4];
    {
        const float4* pb = (const float4*)(prot + ((size_t)(b * L_N + l0 + lt * 16 + col)) * D);
        #pragma unroll
        for (int ks = 0; ks < 4; ++ks) {
            const float4 v0 = pb[ks * 8 + kb * 2];
            const float4 v1 = pb[ks * 8 + kb * 2 + 1];
            const float vv[8] = {v0.x, v0.y, v0.z, v0.w, v1.x, v1.y, v1.z, v1.w};
            short8 bh, bl;
            #pragma unroll
            for (int j = 0; j < 8; ++j) {
                const unsigned short h = f2bf(vv[j]);
                bh[j] = (short)h;
                bl[j] = (short)f2bf(vv[j] - bf2f(h));
            }
            Bh[ks] = bh; Bl[ks] = bl;
        }
    }
    const int s = segoff[b];
    const int n = segoff[b + 1] - s;

    ((float*)rm_part)[tid] = -INFINITY;
    if (tid < 64) ((float*)cm_part)[tid] = -INFINITY;
    __syncthreads();

    float cmrun = -INFINITY;
    for (int at = pair; at * 16 < n; at += 2) {
        const int arow = min(s + at * 16 + col, A_N - 1);
        const unsigned short* xh = Xh + (size_t)arow * D;
        const unsigned short* xl = Xl + (size_t)arow * D;
        short8 Ah[4], Al[4];
        #pragma unroll
        for (int ks = 0; ks < 4; ++ks) {
            Ah[ks] = *(const short8*)(xh + ks * 32 + kb * 8);
            Al[ks] = *(const short8*)(xl + ks * 32 + kb * 8);
        }
        f32x4 aHH = {0.f, 0.f, 0.f, 0.f};
        f32x4 aHL = {0.f, 0.f, 0.f, 0.f};
        f32x4 aLH = {0.f, 0.f, 0.f, 0.f};
        #pragma unroll
        for (int ks = 0; ks < 4; ++ks) {
            aHH = __builtin_amdgcn_mfma_f32_16x16x32_bf16(Ah[ks], Bh[ks], aHH, 0, 0, 0);
            aHL = __builtin_amdgcn_mfma_f32_16x16x32_bf16(Ah[ks], Bl[ks], aHL, 0, 0, 0);
            aLH = __builtin_amdgcn_mfma_f32_16x16x32_bf16(Al[ks], Bh[ks], aLH, 0, 0, 0);
        }
        float r[4];
        #pragma unroll
        for (int i = 0; i < 4; ++i) r[i] = aHH[i] + aHL[i] + aLH[i];

        // rowmax over this tile's 16 l's
        float r0 = r[0], r1 = r[1], r2 = r[2], r3 = r[3];
        #pragma unroll
        for (int off = 1; off <= 8; off <<= 1) {
            r0 = fmaxf(r0, __shfl_xor(r0, off));
            r1 = fmaxf(r1, __shfl_xor(r1, off));
            r2 = fmaxf(r2, __shfl_xor(r2, off));
            r3 = fmaxf(r3, __shfl_xor(r3, off));
        }
        if (col == 0) {
            rm_part[lt][at * 16 + kb * 4 + 0] = r0;
            rm_part[lt][at * 16 + kb * 4 + 1] = r1;
            rm_part[lt][at * 16 + kb * 4 + 2] = r2;
            rm_part[lt][at * 16 + kb * 4 + 3] = r3;
        }
        // colmax over valid atoms of this tile
        const int rb = at * 16 + kb * 4;
        float cm = -INFINITY;
        if (rb + 0 < n) cm = fmaxf(cm, r[0]);
        if (rb + 1 < n) cm = fmaxf(cm, r[1]);
        if (rb + 2 < n) cm = fmaxf(cm, r[2]);
        if (rb + 3 < n) cm = fmaxf(cm, r[3]);
        cm = fmaxf(cm, __shfl_xor(cm, 16));
        cm = fmaxf(cm, __shfl_xor(cm, 32));
        cmrun = fmaxf(cmrun, cm);
    }
    if (kb == 0) cm_part[pair][lt * 16 + col] = cmrun;
    __syncthreads();

    if (tid < 128 && tid < n)
        rowmaxp[(size_t)(s + tid) * NCHUNK + chunk] = fmaxf(rm_part[0][tid], rm_part[1][tid]);
    if (tid >= 128 && tid < 128 + CL) {
        const int l = tid - 128;
        ews_s[l] = expf(fmaxf(cm_part[0][l], cm_part[1][l]));
    }
    __syncthreads();

    if (tid < 32) {
        float v = ews_s[tid];
        #pragma unroll
        for (int off = 1; off <= 16; off <<= 1) v += __shfl_xor(v, off);
        if (tid == 0) eWpart[b * NCHUNK + chunk] = v;
    }

    // prot-pool partial: coalesced re-stream of the chunk (L2-hot)
    const int rg = tid >> 5, c4 = tid & 31;
    float4 pp4 = {0.f, 0.f, 0.f, 0.f};
    const float4* src = (const float4*)(prot + ((size_t)b * L_N + l0) * D);
    #pragma unroll
    for (int q = 0; q < 4; ++q) {
        const int i = tid + q * 256;
        const float4 v = src[i];
        const float wgt = ews_s[i >> 5];
        pp4.x += wgt * v.x; pp4.y += wgt * v.y;
        pp4.z += wgt * v.z; pp4.w += wgt * v.w;
    }
    pred[rg][c4] = pp4;
    __syncthreads();
    if (tid < 32) {
        float4 acc = pred[0][tid];
        #pragma unroll
        for (int gg = 1; gg < 8; ++gg) {
            const float4 t = pred[gg][tid];
            acc.x += t.x; acc.y += t.y; acc.z += t.z; acc.w += t.w;
        }
        float* dst = ppart + (size_t)(b * NCHUNK + chunk) * D + tid * 4;
        dst[0] = acc.x; dst[1] = acc.y; dst[2] = acc.z; dst[3] = acc.w;
    }
}

// ---------- K3: per-molecule pools -> HcT [256][64] ----------
__global__ __launch_bounds__(256) void k3_pool(const float* __restrict__ atom_embed,
                                               const int* __restrict__ segoff,
                                               const float* __restrict__ rowmaxp,
                                               const float* __restrict__ ppart,
                                               const float* __restrict__ eWpart,
                                               float* __restrict__ HcT) {
    __shared__ float red[4];
    __shared__ float coef[512];
    __shared__ float4 pred[8][32];
    const int tid = threadIdx.x;
    const int b = blockIdx.x;
    const int s = segoff[b];
    const int n = segoff[b + 1] - s;

    float local = 0.f;
    for (int j = tid; j < n; j += 256) {
        const float* rp = rowmaxp + (size_t)(s + j) * NCHUNK;
        float m = rp[0];
        #pragma unroll
        for (int c = 1; c < NCHUNK; ++c) m = fmaxf(m, rp[c]);
        local += expf(m);
    }
    const float Sc = blk_sum(local, red, tid);

    const int d4 = tid & 31;
    const int ag = tid >> 5;
    const float4* ae4 = reinterpret_cast<const float4*>(atom_embed);
    float4 pool = {0.f, 0.f, 0.f, 0.f};
    for (int t0 = 0; t0 < n; t0 += 512) {
        const int cnt = min(512, n - t0);
        __syncthreads();
        for (int j = tid; j < cnt; j += 256) {
            const float* rp = rowmaxp + (size_t)(s + t0 + j) * NCHUNK;
            float m = rp[0];
            #pragma unroll
            for (int c = 1; c < NCHUNK; ++c) m = fmaxf(m, rp[c]);
            coef[j] = expf(m) / Sc;
        }
        __syncthreads();
        #pragma unroll 4
        for (int j = ag; j < cnt; j += 8) {
            const float c = coef[j];
            const float4 v = ae4[(size_t)(s + t0 + j) * (D / 4) + d4];
            pool.x += c * v.x; pool.y += c * v.y; pool.z += c * v.z; pool.w += c * v.w;
        }
    }
    __syncthreads();
    pred[ag][d4] = pool;
    __syncthreads();
    if (ag == 0) {
        float4 acc = pred[0][d4];
        #pragma unroll
        for (int gg = 1; gg < 8; ++gg) {
            const float4 t = pred[gg][d4];
            acc.x += t.x; acc.y += t.y; acc.z += t.z; acc.w += t.w;
        }
        HcT[(size_t)(d4 * 4 + 0) * B_N + b] = acc.x;
        HcT[(size_t)(d4 * 4 + 1) * B_N + b] = acc.y;
        HcT[(size_t)(d4 * 4 + 2) * B_N + b] = acc.z;
        HcT[(size_t)(d4 * 4 + 3) * B_N + b] = acc.w;
    }
    if (tid < 128) {
        float v = 0.f, ez = 0.f;
        #pragma unroll
        for (int c = 0; c < NCHUNK; ++c) {
            v  += ppart[(size_t)(b * NCHUNK + c) * D + tid];
            ez += eWpart[b * NCHUNK + c];
        }
        HcT[(size_t)(D + tid) * B_N + b] = v / ez;
    }
}

// ---------- K4: H1T = relu(Hc @ W1 + b1)^T ----------
__global__ __launch_bounds__(256) void k4_h1(const float* __restrict__ HcT,
                                             const float* __restrict__ W1,
                                             const float* __restrict__ b1,
                                             float* __restrict__ H1T) {
    __shared__ float hr[4][64];
    const int tid = threadIdx.x;
    const int m = tid & 63;
    const int jh = (tid >> 6) & 1;
    const int kh = tid >> 7;
    const int j = blockIdx.x * 2 + jh;
    float acc = 0.f;
    const int k0 = kh * 128;
    #pragma unroll 8
    for (int k = k0; k < k0 + 128; ++k)
        acc += HcT[(size_t)k * B_N + m] * W1[(size_t)k * H1_N + j];
    hr[jh * 2 + kh][m] = acc;
    __syncthreads();
    if (kh == 0)
        H1T[(size_t)j * B_N + m] = fmaxf(hr[jh * 2][m] + hr[jh * 2 + 1][m] + b1[j], 0.f);
}

// ---------- K5: H2 + output atomics ----------
__global__ __launch_bounds__(256) void k5_h2(const float* __restrict__ H1T,
                                             const float* __restrict__ W2,
                                             const float* __restrict__ b2,
                                             const float* __restrict__ Wo,
                                             float* __restrict__ out) {
    __shared__ float hr[4][64];
    const int tid = threadIdx.x;
    const int m = tid & 63;
    const int kq = tid >> 6;
    const int j = blockIdx.x;
    float acc = 0.f;
    const int k0 = kq * 128;
    #pragma unroll 8
    for (int k = k0; k < k0 + 128; ++k)
        acc += H1T[(size_t)k * B_N + m] * W2[(size_t)k * H2_N + j];
    hr[kq][m] = acc;
    __syncthreads();
    if (kq == 0) {
        const float h2 = fmaxf(hr[0][m] + hr[1][m] + hr[2][m] + hr[3][m] + b2[j], 0.f);
        atomicAdd(out + m, h2 * Wo[j]);
    }
}

extern "C" void kernel_launch(void* const* d_in, const int* in_sizes, int n_in,
                              void* d_out, int out_size, void* d_ws, size_t ws_size,
                              hipStream_t stream) {
    const float* atom_embed = (const float*)d_in[0];
    const float* prot       = (const float*)d_in[1];
    const int*   splits     = (const int*)d_in[2];
    const float* W_att      = (const float*)d_in[3];
    const float* W1         = (const float*)d_in[4];
    const float* b1         = (const float*)d_in[5];
    const float* W2         = (const float*)d_in[6];
    const float* b2         = (const float*)d_in[7];
    const float* Wo         = (const float*)d_in[8];
    const float* bo         = (const float*)d_in[9];
    float* out = (float*)d_out;

    unsigned short* Xh = (unsigned short*)d_ws;                // A_N*D ushort
    unsigned short* Xl = Xh + (size_t)A_N * D;                 // A_N*D ushort
    float* fp      = (float*)(Xl + (size_t)A_N * D);
    float* rowmaxp = fp;  fp += (size_t)A_N * NCHUNK;          // 32768
    float* ppart   = fp;  fp += (size_t)B_N * NCHUNK * D;      // 131072
    float* eWpart  = fp;  fp += B_N * NCHUNK;                  // 1024
    float* HcT     = fp;  fp += 2 * D * B_N;                   // 16384
    float* H1T     = fp;  fp += H1_N * B_N;                    // 32768
    int*   segoff  = (int*)fp;                                 // 65

    hipLaunchKernelGGL(k1_xmul,  dim3(A_N / 8),        dim3(256), 0, stream,
                       atom_embed, W_att, bo, splits, Xh, Xl, out, segoff);
    hipLaunchKernelGGL(k2_scores, dim3(B_N * NCHUNK),  dim3(256), 0, stream,
                       Xh, Xl, prot, segoff, rowmaxp, ppart, eWpart);
    hipLaunchKernelGGL(k3_pool,  dim3(B_N),            dim3(256), 0, stream,
                       atom_embed, segoff, rowmaxp, ppart, eWpart, HcT);
    hipLaunchKernelGGL(k4_h1,    dim3(H1_N / 2),       dim3(256), 0, stream, HcT, W1, b1, H1T);
    hipLaunchKernelGGL(k5_h2,    dim3(H2_N),           dim3(256), 0, stream, H1T, W2, b2, Wo, out);
}